// Round 8
// baseline (480.652 us; speedup 1.0000x reference)
//
#include <hip/hip_runtime.h>

#define TE 64      // edges per tile (fallback edge kernel)
#define TN 64      // nodes per tile (kernel B)

union F4 { float4 v; float f[4]; };

__device__ __forceinline__ float gelu_f(float x) {
    // jax.nn.gelu(approximate=True): 0.5*x*(1+tanh(sqrt(2/pi)*(x+0.044715*x^3)))
    const float c0 = 0.7978845608028654f;
    float z = c0 * (x + 0.044715f * x * x * x);
    float ez = __builtin_exp2f(z * 2.8853900817779268f);
    float th = 1.0f - 2.0f * __builtin_amdgcn_rcpf(ez + 1.0f);
    return 0.5f * x * (1.0f + th);
}

__device__ __forceinline__ void barrier_lgkm() {
    asm volatile("s_waitcnt lgkmcnt(0)" ::: "memory");
    __builtin_amdgcn_s_barrier();
}

// ---------------- Edge kernel (sorted path): wave-per-edge-range, no LDS ----------------
// lane = channel. W1[64:80,lane] in 16 VGPRs. Each wave walks a contiguous
// dst-sorted range; per-run accumulator -> one atomic row per run.
__global__ __launch_bounds__(256, 8) void edge_run_kernel(
    const float* __restrict__ ef,   // [E,16]
    const int*   __restrict__ eids, // [E] dst-sorted edge ids
    const int2*  __restrict__ sd,   // [E] {src,dst} sorted
    const float* __restrict__ np,   // [N,64] nodePart = nf@W1[0:64]
    const float* __restrict__ W1,   // [80,64]
    const float* __restrict__ b1,   // [64]
    float*       __restrict__ gsum, // [N,64] pre-zeroed
    int nE, int epw)
{
    const int lane = threadIdx.x & 63;
    const int wgid = blockIdx.x * 4 + (threadIdx.x >> 6);
    const int r0 = wgid * epw;
    if (r0 >= nE) return;
    const int r1 = (r0 + epw < nE) ? r0 + epw : nE;

    float W1p[16];
    #pragma unroll
    for (int k = 0; k < 16; ++k)
        W1p[k] = W1[(64 + k) * 64 + lane];
    const float b1v = b1[lane];

    int   cur = -1;
    float run = 0.f;

    for (int e = r0; e < r1; e += 4) {
        const int li  = lane & 3;
        const int idx = (e + li < nE) ? e + li : nE - 1;
        const int  eid4 = eids[idx];
        const int2 sd2  = sd[idx];
        const int  ge   = __shfl(eid4, lane >> 4);
        const float efv = ef[(size_t)ge * 16 + (lane & 15)];

        int srcj[4], dstj[4];
        #pragma unroll
        for (int j = 0; j < 4; ++j) {
            srcj[j] = __shfl(sd2.x, j);
            dstj[j] = __shfl(sd2.y, j);
        }
        float npv[4];
        #pragma unroll
        for (int j = 0; j < 4; ++j)
            npv[j] = np[(size_t)srcj[j] * 64 + lane];

        #pragma unroll
        for (int j = 0; j < 4; ++j) {
            if (e + j < r1) {                      // wave-uniform guard
                float acc = npv[j];
                #pragma unroll
                for (int k = 0; k < 16; ++k)
                    acc = fmaf(__shfl(efv, j * 16 + k), W1p[k], acc);
                const float g = gelu_f(acc + b1v);
                const int d = dstj[j];             // wave-uniform
                if (d != cur) {
                    if (cur >= 0)
                        __hip_atomic_fetch_add(gsum + (size_t)cur * 64 + lane, run,
                                               __ATOMIC_RELAXED, __HIP_MEMORY_SCOPE_AGENT);
                    cur = d;
                    run = 0.f;
                }
                run += g;
            }
        }
    }
    if (cur >= 0)
        __hip_atomic_fetch_add(gsum + (size_t)cur * 64 + lane, run,
                               __ATOMIC_RELAXED, __HIP_MEMORY_SCOPE_AGENT);
}

// ---------------- Fallback edge kernel (block-tile, full GEMM1+GEMM2+atomics) ----------------
__global__ __launch_bounds__(256, 4) void edge_mlp_kernel(
    const float* __restrict__ nf, const float* __restrict__ ef,
    const int* __restrict__ ei,
    const float* __restrict__ W1, const float* __restrict__ b1,
    const float* __restrict__ W2, const float* __restrict__ b2,
    float* agg, int nE, int nTiles)
{
    __shared__ float sX[80][TE + 4];
    __shared__ float sM[64][TE + 4];
    __shared__ int   sDst[TE];

    const int t    = threadIdx.x;
    const int lane = t & 63;
    const int w    = t >> 6;
    const int e0   = (t & 15) * 4;
    const int c0   = (t >> 4) * 4;
    F4 b1v, b2v;
    b1v.v = *(const float4*)(b1 + c0);
    b2v.v = *(const float4*)(b2 + c0);

    for (int tile = blockIdx.x; tile < nTiles; tile += gridDim.x) {
        const int gbase = tile * TE;
        {
            const int idx = gbase + lane;
            const int ge  = idx < nE ? idx : nE - 1;
            const int src = ei[ge];
            const int dstv = (idx < nE) ? ei[nE + ge] : -1;
            const float4* nrow = (const float4*)(nf + (size_t)src * 64);
            F4 a0, a1, a2, a3, ev;
            a0.v = nrow[w * 4 + 0];
            a1.v = nrow[w * 4 + 1];
            a2.v = nrow[w * 4 + 2];
            a3.v = nrow[w * 4 + 3];
            ev.v = *(const float4*)(ef + (size_t)ge * 16 + w * 4);
            const int kb = w * 16;
            #pragma unroll
            for (int j = 0; j < 4; ++j) {
                sX[kb + 0  + j][lane] = a0.f[j];
                sX[kb + 4  + j][lane] = a1.f[j];
                sX[kb + 8  + j][lane] = a2.f[j];
                sX[kb + 12 + j][lane] = a3.f[j];
                sX[64 + w * 4 + j][lane] = ev.f[j];
            }
            if (w == 0) sDst[lane] = dstv;
        }
        barrier_lgkm();

        float acc[4][4] = {};
        #pragma unroll 8
        for (int k = 0; k < 80; ++k) {
            F4 xv, wv;
            xv.v = *(const float4*)&sX[k][e0];
            wv.v = *(const float4*)(W1 + k * 64 + c0);
            #pragma unroll
            for (int i = 0; i < 4; ++i)
                #pragma unroll
                for (int j = 0; j < 4; ++j)
                    acc[i][j] = fmaf(xv.f[i], wv.f[j], acc[i][j]);
        }
        #pragma unroll
        for (int j = 0; j < 4; ++j) {
            F4 col;
            #pragma unroll
            for (int i = 0; i < 4; ++i)
                col.f[i] = gelu_f(acc[i][j] + b1v.f[j]);
            *(float4*)&sM[c0 + j][e0] = col.v;
        }
        barrier_lgkm();

        float acc2[4][4] = {};
        #pragma unroll 8
        for (int k = 0; k < 64; ++k) {
            F4 xv, wv;
            xv.v = *(const float4*)&sM[k][e0];
            wv.v = *(const float4*)(W2 + k * 64 + c0);
            #pragma unroll
            for (int i = 0; i < 4; ++i)
                #pragma unroll
                for (int j = 0; j < 4; ++j)
                    acc2[i][j] = fmaf(xv.f[i], wv.f[j], acc2[i][j]);
        }
        #pragma unroll
        for (int i = 0; i < 4; ++i) {
            if (gbase + e0 + i < nE) {
                float* arow = agg + (size_t)sDst[e0 + i] * 64 + c0;
                #pragma unroll
                for (int j = 0; j < 4; ++j)
                    __hip_atomic_fetch_add(arow + j, acc2[i][j] + b2v.f[j],
                                           __ATOMIC_RELAXED, __HIP_MEMORY_SCOPE_AGENT);
            }
        }
        barrier_lgkm();
    }
}

// ---------------- nodePart = nf @ W1[0:64,:] ----------------
__global__ __launch_bounds__(256) void node_part_kernel(
    const float* __restrict__ nf, const float* __restrict__ W1,
    float* __restrict__ np, int nN)
{
    __shared__ float sU[64][TN + 4];
    const int t = threadIdx.x;
    const int lane = t & 63;
    const int w = t >> 6;
    const int tb = blockIdx.x * TN;
    const int node = (tb + lane < nN) ? tb + lane : nN - 1;
    {
        const float4* nrow = (const float4*)(nf + (size_t)node * 64);
        F4 a0, a1, a2, a3;
        a0.v = nrow[w * 4 + 0];
        a1.v = nrow[w * 4 + 1];
        a2.v = nrow[w * 4 + 2];
        a3.v = nrow[w * 4 + 3];
        const int kb = w * 16;
        #pragma unroll
        for (int j = 0; j < 4; ++j) {
            sU[kb + 0  + j][lane] = a0.f[j];
            sU[kb + 4  + j][lane] = a1.f[j];
            sU[kb + 8  + j][lane] = a2.f[j];
            sU[kb + 12 + j][lane] = a3.f[j];
        }
    }
    barrier_lgkm();
    const int n0 = (t & 15) * 4;
    const int c0 = (t >> 4) * 4;
    float acc[4][4] = {};
    #pragma unroll 8
    for (int k = 0; k < 64; ++k) {
        F4 xv, wv;
        xv.v = *(const float4*)&sU[k][n0];
        wv.v = *(const float4*)(W1 + k * 64 + c0);
        #pragma unroll
        for (int i = 0; i < 4; ++i)
            #pragma unroll
            for (int j = 0; j < 4; ++j)
                acc[i][j] = fmaf(xv.f[i], wv.f[j], acc[i][j]);
    }
    #pragma unroll
    for (int i = 0; i < 4; ++i) {
        const int gnode = tb + n0 + i;
        if (gnode < nN) {
            F4 o;
            #pragma unroll
            for (int j = 0; j < 4; ++j) o.f[j] = acc[i][j];
            *(float4*)(np + (size_t)gnode * 64 + c0) = o.v;
        }
    }
}

// ---------------- W23 = W2 @ W3[64:128,:], b2w = b2 @ W3[64:128,:] ----------------
__global__ void prep_w23_kernel(const float* __restrict__ W2, const float* __restrict__ W3,
                                const float* __restrict__ b2,
                                float* __restrict__ W23, float* __restrict__ b2w)
{
    const int t = threadIdx.x;           // 256
    const int c = t & 63;
    const int kg = t >> 6;
    for (int k = kg * 16; k < kg * 16 + 16; ++k) {
        float s = 0.f;
        for (int m = 0; m < 64; ++m)
            s = fmaf(W2[k * 64 + m], W3[(64 + m) * 64 + c], s);
        W23[k * 64 + c] = s;
    }
    if (t < 64) {
        float s = 0.f;
        for (int m = 0; m < 64; ++m)
            s = fmaf(b2[m], W3[(64 + m) * 64 + t], s);
        b2w[t] = s;
    }
}

// ---------------- CSR build ----------------
__global__ __launch_bounds__(256) void hist_kernel(const int* __restrict__ dst,
                                                   int* __restrict__ counts, int nE) {
    int e = blockIdx.x * 256 + threadIdx.x;
    const int stride = gridDim.x * 256;
    for (; e < nE; e += stride)
        atomicAdd(&counts[dst[e]], 1);
}

__global__ __launch_bounds__(256) void scan_local_kernel(const int* __restrict__ in,
                                                         int* __restrict__ out,
                                                         int* __restrict__ bsum, int n) {
    __shared__ int s[256];
    const int t = threadIdx.x;
    const int base = blockIdx.x * 2048 + t * 8;
    int v[8];
    #pragma unroll
    for (int i = 0; i < 8; ++i) v[i] = (base + i < n) ? in[base + i] : 0;
    int run = 0;
    #pragma unroll
    for (int i = 0; i < 8; ++i) { int c = v[i]; v[i] = run; run += c; }
    s[t] = run;
    __syncthreads();
    int x = run;
    for (int off = 1; off < 256; off <<= 1) {
        int y = (t >= off) ? s[t - off] : 0;
        __syncthreads();
        x += y; s[t] = x;
        __syncthreads();
    }
    const int texcl = x - run;
    if (t == 255) bsum[blockIdx.x] = x;
    #pragma unroll
    for (int i = 0; i < 8; ++i)
        if (base + i < n) out[base + i] = texcl + v[i];
}

__global__ void scan_bsums_kernel(int* bsum, int nb) {
    const int l = threadIdx.x;   // 64 threads
    if (nb <= 64) {
        int v = (l < nb) ? bsum[l] : 0;
        const int orig = v;
        for (int off = 1; off < 64; off <<= 1) {
            int y = __shfl_up(v, off, 64);
            if (l >= off) v += y;
        }
        if (l < nb) bsum[l] = v - orig;   // exclusive
    } else if (l == 0) {
        int run = 0;
        for (int b = 0; b < nb; ++b) { int tt = bsum[b]; bsum[b] = run; run += tt; }
    }
}

__global__ __launch_bounds__(256) void scan_add_kernel(int* __restrict__ offs,
                                                       const int* __restrict__ bsum,
                                                       int* __restrict__ cursor, int n) {
    const int base = blockIdx.x * 2048 + threadIdx.x * 8;
    const int add = bsum[blockIdx.x];
    #pragma unroll
    for (int i = 0; i < 8; ++i)
        if (base + i < n) { int v = offs[base + i] + add; offs[base + i] = v; cursor[base + i] = v; }
}

__global__ __launch_bounds__(256) void scatter_kernel(const int* __restrict__ ei,
                                                      int* __restrict__ cursor,
                                                      int* __restrict__ eids,
                                                      int2* __restrict__ sd, int nE) {
    int e = blockIdx.x * 256 + threadIdx.x;
    const int stride = gridDim.x * 256;
    for (; e < nE; e += stride) {
        const int s = ei[e];
        const int d = ei[nE + e];
        const int pos = atomicAdd(&cursor[d], 1);
        eids[pos] = e;
        sd[pos] = make_int2(s, d);
    }
}

// ---------------- Kernel B: node update + LayerNorm + GELU + residual ----------------
__global__ __launch_bounds__(256) void node_update_kernel(
    const float* __restrict__ nf,
    const float* gsum,               // may alias out
    const float* __restrict__ W3,    // rows 0..63
    const float* __restrict__ wB,    // rows 64..127 (W23 or W3+4096)
    const float* __restrict__ b3,
    const float* __restrict__ cvec,  // b2w or null
    const int*   __restrict__ counts,// [N] or null
    const float* __restrict__ lns,
    const float* __restrict__ lnb,
    float* out, int nN)
{
    __shared__ float sW3[128][64];
    __shared__ float sU[128][TN + 4];
    __shared__ float sP1[16][TN];
    __shared__ float sP2[16][TN];
    __shared__ float sMu[TN];
    __shared__ float sRs[TN];

    const int t = threadIdx.x;
    for (int i = t * 4; i < 64 * 64; i += 1024)
        *(float4*)((float*)sW3 + i) = *(const float4*)(W3 + i);
    for (int i = t * 4; i < 64 * 64; i += 1024)
        *(float4*)((float*)sW3 + 4096 + i) = *(const float4*)(wB + i);

    const int lane = t & 63;
    const int w    = t >> 6;
    const int tb   = blockIdx.x * TN;
    const int node = tb + lane;
    const bool valid = node < nN;

    {
        const float* base = (w < 2) ? (nf   + (size_t)node * 64 + w * 32)
                                    : (gsum + (size_t)node * 64 + (w - 2) * 32);
        const int kb = (w < 2) ? (w * 32) : (64 + (w - 2) * 32);
        #pragma unroll
        for (int q = 0; q < 8; ++q) {
            F4 v;
            v.v = valid ? *(const float4*)(base + q * 4) : make_float4(0.f, 0.f, 0.f, 0.f);
            #pragma unroll
            for (int j = 0; j < 4; ++j)
                sU[kb + q * 4 + j][lane] = v.f[j];
        }
    }

    const int n0 = (t & 15) * 4;
    const int c0 = (t >> 4) * 4;
    F4 b3v, sv, bv, cv;
    b3v.v = *(const float4*)(b3  + c0);
    sv.v  = *(const float4*)(lns + c0);
    bv.v  = *(const float4*)(lnb + c0);
    if (cvec) cv.v = *(const float4*)(cvec + c0);
    __syncthreads();

    float acc[4][4] = {};
    #pragma unroll 8
    for (int k = 0; k < 128; ++k) {
        F4 xv, wv;
        xv.v = *(const float4*)&sU[k][n0];
        wv.v = *(const float4*)&sW3[k][c0];
        #pragma unroll
        for (int i = 0; i < 4; ++i)
            #pragma unroll
            for (int j = 0; j < 4; ++j)
                acc[i][j] = fmaf(xv.f[i], wv.f[j], acc[i][j]);
    }

    float h[4][4];
    #pragma unroll
    for (int i = 0; i < 4; ++i) {
        float cf = 0.f;
        if (counts) {
            const int gnode = tb + n0 + i;
            cf = (float)counts[gnode < nN ? gnode : nN - 1];
        }
        #pragma unroll
        for (int j = 0; j < 4; ++j) {
            float v = acc[i][j] + b3v.f[j];
            if (cvec) v = fmaf(cf, cv.f[j], v);
            h[i][j] = v;
        }
    }

    const int cg = t >> 4;
    #pragma unroll
    for (int i = 0; i < 4; ++i) {
        float s1 = h[i][0] + h[i][1] + h[i][2] + h[i][3];
        float s2 = h[i][0]*h[i][0] + h[i][1]*h[i][1] + h[i][2]*h[i][2] + h[i][3]*h[i][3];
        sP1[cg][n0 + i] = s1;
        sP2[cg][n0 + i] = s2;
    }
    __syncthreads();
    if (t < TN) {
        float m1 = 0.f, m2 = 0.f;
        #pragma unroll
        for (int g = 0; g < 16; ++g) { m1 += sP1[g][t]; m2 += sP2[g][t]; }
        float mu  = m1 * (1.f / 64.f);
        float var = m2 * (1.f / 64.f) - mu * mu;
        sMu[t] = mu;
        sRs[t] = rsqrtf(var + 1e-6f);
    }
    __syncthreads();

    #pragma unroll
    for (int i = 0; i < 4; ++i) {
        const int gnode = tb + n0 + i;
        const float mu = sMu[n0 + i];
        const float rs = sRs[n0 + i];
        if (gnode < nN) {
            #pragma unroll
            for (int j = 0; j < 4; ++j) {
                float xn = (h[i][j] - mu) * rs * sv.f[j] + bv.f[j];
                float r  = gelu_f(xn) + sU[c0 + j][n0 + i];
                out[(size_t)gnode * 64 + c0 + j] = r;
            }
        }
    }
}

extern "C" void kernel_launch(void* const* d_in, const int* in_sizes, int n_in,
                              void* d_out, int out_size, void* d_ws, size_t ws_size,
                              hipStream_t stream)
{
    const float* nf  = (const float*)d_in[0];
    const float* ef  = (const float*)d_in[1];
    const int*   ei  = (const int*)  d_in[2];
    const float* W1  = (const float*)d_in[3];
    const float* b1  = (const float*)d_in[4];
    const float* W2  = (const float*)d_in[5];
    const float* b2  = (const float*)d_in[6];
    const float* W3  = (const float*)d_in[7];
    const float* b3  = (const float*)d_in[8];
    const float* lns = (const float*)d_in[9];
    const float* lnb = (const float*)d_in[10];

    const int nN = in_sizes[0] / 64;
    const int nE = in_sizes[2] / 2;
    float* out = (float*)d_out;
    const int* dstArr = ei + nE;

    const int gridB = (nN + TN - 1) / TN;

    // ws layout: CSR + folded weights (small) -> nodePart -> gSum
    char* ws = (char*)d_ws;
    size_t off = 0;
    auto take = [&](size_t bytes) { void* p = ws + off; off = (off + bytes + 255) & ~(size_t)255; return p; };
    int*   counts = (int*)  take((size_t)nN * 4);
    int*   offs   = (int*)  take((size_t)nN * 4);
    int*   cursor = (int*)  take((size_t)nN * 4);
    int*   bsum   = (int*)  take(4096);
    int*   eids   = (int*)  take((size_t)nE * 4);
    int2*  sd     = (int2*) take((size_t)nE * 8);
    float* W23    = (float*)take(64 * 64 * 4);
    float* b2w    = (float*)take(64 * 4);
    float* npart  = (float*)take((size_t)nN * 64 * 4);
    const size_t tier2End = off;
    float* gsumw  = (float*)take((size_t)nN * 64 * 4);
    const size_t tier3End = off;
    const size_t aggBytes = (size_t)nN * 64 * 4;

    if (ws_size >= tier2End) {
        // ---- fast path: CSR + nodePart + wave-per-run edge kernel ----
        float* gsum = (ws_size >= tier3End) ? gsumw : out;  // aliasing out is safe (block-local RAW)
        const int nb = (nN + 2047) / 2048;
        hipMemsetAsync(counts, 0, (size_t)nN * 4, stream);
        hipMemsetAsync(gsum, 0, aggBytes, stream);
        hipLaunchKernelGGL(hist_kernel, dim3(2048), dim3(256), 0, stream, dstArr, counts, nE);
        hipLaunchKernelGGL(scan_local_kernel, dim3(nb), dim3(256), 0, stream, counts, offs, bsum, nN);
        hipLaunchKernelGGL(scan_bsums_kernel, dim3(1), dim3(64), 0, stream, bsum, nb);
        hipLaunchKernelGGL(scan_add_kernel, dim3(nb), dim3(256), 0, stream, offs, bsum, cursor, nN);
        hipLaunchKernelGGL(scatter_kernel, dim3(2048), dim3(256), 0, stream, ei, cursor, eids, sd, nE);
        hipLaunchKernelGGL(prep_w23_kernel, dim3(1), dim3(256), 0, stream, W2, W3, b2, W23, b2w);
        hipLaunchKernelGGL(node_part_kernel, dim3(gridB), dim3(256), 0, stream, nf, W1, npart, nN);

        const int gridE = 2048;                         // 8192 waves
        const int epw   = (nE + gridE * 4 - 1) / (gridE * 4);
        hipLaunchKernelGGL(edge_run_kernel, dim3(gridE), dim3(256), 0, stream,
                           ef, eids, sd, npart, W1, b1, gsum, nE, epw);

        hipLaunchKernelGGL(node_update_kernel, dim3(gridB), dim3(256), 0, stream,
                           nf, gsum, W3, W23, b3, b2w, counts, lns, lnb, out, nN);
    } else {
        // ---- fallback: block-tile edge kernel with per-edge atomics ----
        const int nTiles = (nE + TE - 1) / TE;
        const int gridA  = nTiles < 1024 ? nTiles : 1024;
        float* agg = (ws_size >= aggBytes) ? (float*)d_ws : out;
        hipMemsetAsync(agg, 0, aggBytes, stream);
        hipLaunchKernelGGL(edge_mlp_kernel, dim3(gridA), dim3(256), 0, stream,
                           nf, ef, ei, W1, b1, W2, b2, agg, nE, nTiles);
        hipLaunchKernelGGL(node_update_kernel, dim3(gridB), dim3(256), 0, stream,
                           nf, agg, W3, W3 + 64 * 64, b3, (const float*)nullptr, (const int*)nullptr,
                           lns, lnb, out, nN);
    }
}

// Round 9
// 413.050 us; speedup vs baseline: 1.1637x; 1.1637x over previous
//
#include <hip/hip_runtime.h>

#define TE 64      // edges per tile
#define TN 64      // nodes per tile (kernel B)

union F4 { float4 v; float f[4]; };

__device__ __forceinline__ float gelu_f(float x) {
    // jax.nn.gelu(approximate=True): 0.5*x*(1+tanh(sqrt(2/pi)*(x+0.044715*x^3)))
    const float c0 = 0.7978845608028654f;
    float z = c0 * (x + 0.044715f * x * x * x);
    float ez = __builtin_exp2f(z * 2.8853900817779268f);
    float th = 1.0f - 2.0f * __builtin_amdgcn_rcpf(ez + 1.0f);
    return 0.5f * x * (1.0f + th);
}

__device__ __forceinline__ void barrier_lgkm() {
    asm volatile("s_waitcnt lgkmcnt(0)" ::: "memory");
    __builtin_amdgcn_s_barrier();
}

// ---------------- Edge kernel (sorted + nodePart): small-LDS block-tile ----------------
// GEMM1 = ef@W1[64:80] + np[src]; gelu; per-tile segmented reduction into gsum.
// LDS ~22.5KB -> 6 blocks/CU for np-gather latency hiding.
__global__ __launch_bounds__(256, 6) void edge_np_kernel(
    const float* __restrict__ ef,   // [E,16]
    const int4*  __restrict__ esd,  // [E] {src,dst,eid,-} dst-sorted
    const float* __restrict__ np,   // [N,64] nodePart = nf@W1[0:64]
    const float* __restrict__ W1,   // [80,64]
    const float* __restrict__ b1,   // [64]
    float*       __restrict__ gsum, // [N,64] pre-zeroed
    int nE, int nTiles)
{
    __shared__ float sX[16][TE + 4];   // ef transposed [k][e]
    __shared__ float sM[64][TE + 4];   // gelu(msg1) transposed [c][e]
    __shared__ int   sDst[TE];
    __shared__ int   sSrc[TE];

    const int t    = threadIdx.x;
    const int lane = t & 63;
    const int w    = t >> 6;          // wave id 0..3
    const int e0   = (t & 15) * 4;    // microtile edges
    const int c0   = (t >> 4) * 4;    // microtile channels
    F4 b1v;
    b1v.v = *(const float4*)(b1 + c0);

    for (int tile = blockIdx.x; tile < nTiles; tile += gridDim.x) {
        const int gbase = tile * TE;
        // ---- gather: lane = edge, wave = 4-feature chunk ----
        {
            const int idx = gbase + lane;
            const int ci  = idx < nE ? idx : nE - 1;    // clamp (tail-safe)
            const int4 e  = esd[ci];
            F4 ev;
            ev.v = *(const float4*)(ef + (size_t)e.z * 16 + w * 4);
            #pragma unroll
            for (int j = 0; j < 4; ++j)
                sX[w * 4 + j][lane] = ev.f[j];
            if (w == 0) sDst[lane] = (idx < nE) ? e.y : -1;   // sentinel pad
            if (w == 1) sSrc[lane] = e.x;
        }
        barrier_lgkm();

        // ---- GEMM1 (16 k-iters) + np[src] add ----
        float acc[4][4] = {};
        #pragma unroll
        for (int k = 0; k < 16; ++k) {
            F4 xv, wv;
            xv.v = *(const float4*)&sX[k][e0];
            wv.v = *(const float4*)(W1 + (64 + k) * 64 + c0);
            #pragma unroll
            for (int i = 0; i < 4; ++i)
                #pragma unroll
                for (int j = 0; j < 4; ++j)
                    acc[i][j] = fmaf(xv.f[i], wv.f[j], acc[i][j]);
        }
        #pragma unroll
        for (int i = 0; i < 4; ++i) {
            F4 npv;
            npv.v = *(const float4*)(np + (size_t)sSrc[e0 + i] * 64 + c0);
            #pragma unroll
            for (int j = 0; j < 4; ++j)
                acc[i][j] += npv.f[j];
        }

        // gelu + write transposed
        #pragma unroll
        for (int j = 0; j < 4; ++j) {
            F4 col;
            #pragma unroll
            for (int i = 0; i < 4; ++i)
                col.f[i] = gelu_f(acc[i][j] + b1v.f[j]);
            *(float4*)&sM[c0 + j][e0] = col.v;
        }
        barrier_lgkm();

        // ---- segmented reduction along sorted-edge axis ----
        const int c  = t >> 2;
        const int q  = t & 3;
        const int cb = q * 16;
        int   cur = -1;
        float run = 0.f;
        #pragma unroll
        for (int s = 0; s < 4; ++s) {
            F4 rv;
            rv.v = *(const float4*)&sM[c][cb + s * 4];
            #pragma unroll
            for (int j = 0; j < 4; ++j) {
                const int d = sDst[cb + s * 4 + j];
                if (d != cur) {
                    if (cur >= 0)
                        __hip_atomic_fetch_add(gsum + (size_t)cur * 64 + c, run,
                                               __ATOMIC_RELAXED, __HIP_MEMORY_SCOPE_AGENT);
                    cur = d;
                    run = 0.f;
                }
                if (d >= 0) run += rv.f[j];
            }
        }
        if (cur >= 0)
            __hip_atomic_fetch_add(gsum + (size_t)cur * 64 + c, run,
                                   __ATOMIC_RELAXED, __HIP_MEMORY_SCOPE_AGENT);
        barrier_lgkm();   // protect sM/sDst/sSrc before next gather
    }
}

// ---------------- Fallback edge kernel (block-tile, full GEMM1+GEMM2+atomics) ----------------
__global__ __launch_bounds__(256, 4) void edge_mlp_kernel(
    const float* __restrict__ nf, const float* __restrict__ ef,
    const int* __restrict__ ei,
    const float* __restrict__ W1, const float* __restrict__ b1,
    const float* __restrict__ W2, const float* __restrict__ b2,
    float* agg, int nE, int nTiles)
{
    __shared__ float sX[80][TE + 4];
    __shared__ float sM[64][TE + 4];
    __shared__ int   sDst[TE];

    const int t    = threadIdx.x;
    const int lane = t & 63;
    const int w    = t >> 6;
    const int e0   = (t & 15) * 4;
    const int c0   = (t >> 4) * 4;
    F4 b1v, b2v;
    b1v.v = *(const float4*)(b1 + c0);
    b2v.v = *(const float4*)(b2 + c0);

    for (int tile = blockIdx.x; tile < nTiles; tile += gridDim.x) {
        const int gbase = tile * TE;
        {
            const int idx = gbase + lane;
            const int ge  = idx < nE ? idx : nE - 1;
            const int src = ei[ge];
            const int dstv = (idx < nE) ? ei[nE + ge] : -1;
            const float4* nrow = (const float4*)(nf + (size_t)src * 64);
            F4 a0, a1, a2, a3, ev;
            a0.v = nrow[w * 4 + 0];
            a1.v = nrow[w * 4 + 1];
            a2.v = nrow[w * 4 + 2];
            a3.v = nrow[w * 4 + 3];
            ev.v = *(const float4*)(ef + (size_t)ge * 16 + w * 4);
            const int kb = w * 16;
            #pragma unroll
            for (int j = 0; j < 4; ++j) {
                sX[kb + 0  + j][lane] = a0.f[j];
                sX[kb + 4  + j][lane] = a1.f[j];
                sX[kb + 8  + j][lane] = a2.f[j];
                sX[kb + 12 + j][lane] = a3.f[j];
                sX[64 + w * 4 + j][lane] = ev.f[j];
            }
            if (w == 0) sDst[lane] = dstv;
        }
        barrier_lgkm();

        float acc[4][4] = {};
        #pragma unroll 8
        for (int k = 0; k < 80; ++k) {
            F4 xv, wv;
            xv.v = *(const float4*)&sX[k][e0];
            wv.v = *(const float4*)(W1 + k * 64 + c0);
            #pragma unroll
            for (int i = 0; i < 4; ++i)
                #pragma unroll
                for (int j = 0; j < 4; ++j)
                    acc[i][j] = fmaf(xv.f[i], wv.f[j], acc[i][j]);
        }
        #pragma unroll
        for (int j = 0; j < 4; ++j) {
            F4 col;
            #pragma unroll
            for (int i = 0; i < 4; ++i)
                col.f[i] = gelu_f(acc[i][j] + b1v.f[j]);
            *(float4*)&sM[c0 + j][e0] = col.v;
        }
        barrier_lgkm();

        float acc2[4][4] = {};
        #pragma unroll 8
        for (int k = 0; k < 64; ++k) {
            F4 xv, wv;
            xv.v = *(const float4*)&sM[k][e0];
            wv.v = *(const float4*)(W2 + k * 64 + c0);
            #pragma unroll
            for (int i = 0; i < 4; ++i)
                #pragma unroll
                for (int j = 0; j < 4; ++j)
                    acc2[i][j] = fmaf(xv.f[i], wv.f[j], acc2[i][j]);
        }
        #pragma unroll
        for (int i = 0; i < 4; ++i) {
            if (gbase + e0 + i < nE) {
                float* arow = agg + (size_t)sDst[e0 + i] * 64 + c0;
                #pragma unroll
                for (int j = 0; j < 4; ++j)
                    __hip_atomic_fetch_add(arow + j, acc2[i][j] + b2v.f[j],
                                           __ATOMIC_RELAXED, __HIP_MEMORY_SCOPE_AGENT);
            }
        }
        barrier_lgkm();
    }
}

// ---------------- nodePart = nf @ W1[0:64,:] ----------------
__global__ __launch_bounds__(256) void node_part_kernel(
    const float* __restrict__ nf, const float* __restrict__ W1,
    float* __restrict__ np, int nN)
{
    __shared__ float sU[64][TN + 4];
    const int t = threadIdx.x;
    const int lane = t & 63;
    const int w = t >> 6;
    const int tb = blockIdx.x * TN;
    const int node = (tb + lane < nN) ? tb + lane : nN - 1;
    {
        const float4* nrow = (const float4*)(nf + (size_t)node * 64);
        F4 a0, a1, a2, a3;
        a0.v = nrow[w * 4 + 0];
        a1.v = nrow[w * 4 + 1];
        a2.v = nrow[w * 4 + 2];
        a3.v = nrow[w * 4 + 3];
        const int kb = w * 16;
        #pragma unroll
        for (int j = 0; j < 4; ++j) {
            sU[kb + 0  + j][lane] = a0.f[j];
            sU[kb + 4  + j][lane] = a1.f[j];
            sU[kb + 8  + j][lane] = a2.f[j];
            sU[kb + 12 + j][lane] = a3.f[j];
        }
    }
    barrier_lgkm();
    const int n0 = (t & 15) * 4;
    const int c0 = (t >> 4) * 4;
    float acc[4][4] = {};
    #pragma unroll 8
    for (int k = 0; k < 64; ++k) {
        F4 xv, wv;
        xv.v = *(const float4*)&sU[k][n0];
        wv.v = *(const float4*)(W1 + k * 64 + c0);
        #pragma unroll
        for (int i = 0; i < 4; ++i)
            #pragma unroll
            for (int j = 0; j < 4; ++j)
                acc[i][j] = fmaf(xv.f[i], wv.f[j], acc[i][j]);
    }
    #pragma unroll
    for (int i = 0; i < 4; ++i) {
        const int gnode = tb + n0 + i;
        if (gnode < nN) {
            F4 o;
            #pragma unroll
            for (int j = 0; j < 4; ++j) o.f[j] = acc[i][j];
            *(float4*)(np + (size_t)gnode * 64 + c0) = o.v;
        }
    }
}

// ---------------- W23 = W2 @ W3[64:128,:], b2w = b2 @ W3[64:128,:] ----------------
__global__ void prep_w23_kernel(const float* __restrict__ W2, const float* __restrict__ W3,
                                const float* __restrict__ b2,
                                float* __restrict__ W23, float* __restrict__ b2w)
{
    const int t = threadIdx.x;           // 256
    const int c = t & 63;
    const int kg = t >> 6;
    for (int k = kg * 16; k < kg * 16 + 16; ++k) {
        float s = 0.f;
        for (int m = 0; m < 64; ++m)
            s = fmaf(W2[k * 64 + m], W3[(64 + m) * 64 + c], s);
        W23[k * 64 + c] = s;
    }
    if (t < 64) {
        float s = 0.f;
        for (int m = 0; m < 64; ++m)
            s = fmaf(b2[m], W3[(64 + m) * 64 + t], s);
        b2w[t] = s;
    }
}

// ---------------- CSR build ----------------
__global__ __launch_bounds__(256) void hist_kernel(const int* __restrict__ dst,
                                                   int* __restrict__ counts, int nE) {
    int e = blockIdx.x * 256 + threadIdx.x;
    const int stride = gridDim.x * 256;
    for (; e < nE; e += stride)
        atomicAdd(&counts[dst[e]], 1);
}

__global__ __launch_bounds__(256) void scan_local_kernel(const int* __restrict__ in,
                                                         int* __restrict__ out,
                                                         int* __restrict__ bsum, int n) {
    __shared__ int s[256];
    const int t = threadIdx.x;
    const int base = blockIdx.x * 2048 + t * 8;
    int v[8];
    #pragma unroll
    for (int i = 0; i < 8; ++i) v[i] = (base + i < n) ? in[base + i] : 0;
    int run = 0;
    #pragma unroll
    for (int i = 0; i < 8; ++i) { int c = v[i]; v[i] = run; run += c; }
    s[t] = run;
    __syncthreads();
    int x = run;
    for (int off = 1; off < 256; off <<= 1) {
        int y = (t >= off) ? s[t - off] : 0;
        __syncthreads();
        x += y; s[t] = x;
        __syncthreads();
    }
    const int texcl = x - run;
    if (t == 255) bsum[blockIdx.x] = x;
    #pragma unroll
    for (int i = 0; i < 8; ++i)
        if (base + i < n) out[base + i] = texcl + v[i];
}

__global__ void scan_bsums_kernel(int* bsum, int nb) {
    const int l = threadIdx.x;   // 64 threads
    if (nb <= 64) {
        int v = (l < nb) ? bsum[l] : 0;
        const int orig = v;
        for (int off = 1; off < 64; off <<= 1) {
            int y = __shfl_up(v, off, 64);
            if (l >= off) v += y;
        }
        if (l < nb) bsum[l] = v - orig;   // exclusive
    } else if (l == 0) {
        int run = 0;
        for (int b = 0; b < nb; ++b) { int tt = bsum[b]; bsum[b] = run; run += tt; }
    }
}

__global__ __launch_bounds__(256) void scan_add_kernel(int* __restrict__ offs,
                                                       const int* __restrict__ bsum,
                                                       int* __restrict__ cursor, int n) {
    const int base = blockIdx.x * 2048 + threadIdx.x * 8;
    const int add = bsum[blockIdx.x];
    #pragma unroll
    for (int i = 0; i < 8; ++i)
        if (base + i < n) { int v = offs[base + i] + add; offs[base + i] = v; cursor[base + i] = v; }
}

__global__ __launch_bounds__(256) void scatter_kernel(const int* __restrict__ ei,
                                                      int* __restrict__ cursor,
                                                      int4* __restrict__ esd, int nE) {
    int e = blockIdx.x * 256 + threadIdx.x;
    const int stride = gridDim.x * 256;
    for (; e < nE; e += stride) {
        const int s = ei[e];
        const int d = ei[nE + e];
        const int pos = atomicAdd(&cursor[d], 1);
        esd[pos] = make_int4(s, d, e, 0);
    }
}

// ---------------- Kernel B: node update + LayerNorm + GELU + residual ----------------
__global__ __launch_bounds__(256) void node_update_kernel(
    const float* __restrict__ nf,
    const float* gsum,               // may alias out
    const float* __restrict__ W3,    // rows 0..63
    const float* __restrict__ wB,    // rows 64..127 (W23 or W3+4096)
    const float* __restrict__ b3,
    const float* __restrict__ cvec,  // b2w or null
    const int*   __restrict__ counts,// [N] or null
    const float* __restrict__ lns,
    const float* __restrict__ lnb,
    float* out, int nN)
{
    __shared__ float sW3[128][64];
    __shared__ float sU[128][TN + 4];
    __shared__ float sP1[16][TN];
    __shared__ float sP2[16][TN];
    __shared__ float sMu[TN];
    __shared__ float sRs[TN];

    const int t = threadIdx.x;
    for (int i = t * 4; i < 64 * 64; i += 1024)
        *(float4*)((float*)sW3 + i) = *(const float4*)(W3 + i);
    for (int i = t * 4; i < 64 * 64; i += 1024)
        *(float4*)((float*)sW3 + 4096 + i) = *(const float4*)(wB + i);

    const int lane = t & 63;
    const int w    = t >> 6;
    const int tb   = blockIdx.x * TN;
    const int node = tb + lane;
    const bool valid = node < nN;

    {
        const float* base = (w < 2) ? (nf   + (size_t)node * 64 + w * 32)
                                    : (gsum + (size_t)node * 64 + (w - 2) * 32);
        const int kb = (w < 2) ? (w * 32) : (64 + (w - 2) * 32);
        #pragma unroll
        for (int q = 0; q < 8; ++q) {
            F4 v;
            v.v = valid ? *(const float4*)(base + q * 4) : make_float4(0.f, 0.f, 0.f, 0.f);
            #pragma unroll
            for (int j = 0; j < 4; ++j)
                sU[kb + q * 4 + j][lane] = v.f[j];
        }
    }

    const int n0 = (t & 15) * 4;
    const int c0 = (t >> 4) * 4;
    F4 b3v, sv, bv, cv;
    b3v.v = *(const float4*)(b3  + c0);
    sv.v  = *(const float4*)(lns + c0);
    bv.v  = *(const float4*)(lnb + c0);
    if (cvec) cv.v = *(const float4*)(cvec + c0);
    __syncthreads();

    float acc[4][4] = {};
    #pragma unroll 8
    for (int k = 0; k < 128; ++k) {
        F4 xv, wv;
        xv.v = *(const float4*)&sU[k][n0];
        wv.v = *(const float4*)&sW3[k][c0];
        #pragma unroll
        for (int i = 0; i < 4; ++i)
            #pragma unroll
            for (int j = 0; j < 4; ++j)
                acc[i][j] = fmaf(xv.f[i], wv.f[j], acc[i][j]);
    }

    float h[4][4];
    #pragma unroll
    for (int i = 0; i < 4; ++i) {
        float cf = 0.f;
        if (counts) {
            const int gnode = tb + n0 + i;
            cf = (float)counts[gnode < nN ? gnode : nN - 1];
        }
        #pragma unroll
        for (int j = 0; j < 4; ++j) {
            float v = acc[i][j] + b3v.f[j];
            if (cvec) v = fmaf(cf, cv.f[j], v);
            h[i][j] = v;
        }
    }

    const int cg = t >> 4;
    #pragma unroll
    for (int i = 0; i < 4; ++i) {
        float s1 = h[i][0] + h[i][1] + h[i][2] + h[i][3];
        float s2 = h[i][0]*h[i][0] + h[i][1]*h[i][1] + h[i][2]*h[i][2] + h[i][3]*h[i][3];
        sP1[cg][n0 + i] = s1;
        sP2[cg][n0 + i] = s2;
    }
    __syncthreads();
    if (t < TN) {
        float m1 = 0.f, m2 = 0.f;
        #pragma unroll
        for (int g = 0; g < 16; ++g) { m1 += sP1[g][t]; m2 += sP2[g][t]; }
        float mu  = m1 * (1.f / 64.f);
        float var = m2 * (1.f / 64.f) - mu * mu;
        sMu[t] = mu;
        sRs[t] = rsqrtf(var + 1e-6f);
    }
    __syncthreads();

    #pragma unroll
    for (int i = 0; i < 4; ++i) {
        const int gnode = tb + n0 + i;
        const float mu = sMu[n0 + i];
        const float rs = sRs[n0 + i];
        if (gnode < nN) {
            #pragma unroll
            for (int j = 0; j < 4; ++j) {
                float xn = (h[i][j] - mu) * rs * sv.f[j] + bv.f[j];
                float r  = gelu_f(xn) + sU[c0 + j][n0 + i];
                out[(size_t)gnode * 64 + c0 + j] = r;
            }
        }
    }
}

extern "C" void kernel_launch(void* const* d_in, const int* in_sizes, int n_in,
                              void* d_out, int out_size, void* d_ws, size_t ws_size,
                              hipStream_t stream)
{
    const float* nf  = (const float*)d_in[0];
    const float* ef  = (const float*)d_in[1];
    const int*   ei  = (const int*)  d_in[2];
    const float* W1  = (const float*)d_in[3];
    const float* b1  = (const float*)d_in[4];
    const float* W2  = (const float*)d_in[5];
    const float* b2  = (const float*)d_in[6];
    const float* W3  = (const float*)d_in[7];
    const float* b3  = (const float*)d_in[8];
    const float* lns = (const float*)d_in[9];
    const float* lnb = (const float*)d_in[10];

    const int nN = in_sizes[0] / 64;
    const int nE = in_sizes[2] / 2;
    float* out = (float*)d_out;
    const int* dstArr = ei + nE;

    const int gridB = (nN + TN - 1) / TN;
    const int nTiles = (nE + TE - 1) / TE;

    // ws layout: CSR + folded weights -> nodePart -> gSum
    char* ws = (char*)d_ws;
    size_t off = 0;
    auto take = [&](size_t bytes) { void* p = ws + off; off = (off + bytes + 255) & ~(size_t)255; return p; };
    int*   counts = (int*)  take((size_t)nN * 4);
    int*   offs   = (int*)  take((size_t)nN * 4);
    int*   cursor = (int*)  take((size_t)nN * 4);
    int*   bsum   = (int*)  take(4096);
    int4*  esd    = (int4*) take((size_t)nE * 16);
    float* W23    = (float*)take(64 * 64 * 4);
    float* b2w    = (float*)take(64 * 4);
    float* npart  = (float*)take((size_t)nN * 64 * 4);
    const size_t tier2End = off;
    float* gsumw  = (float*)take((size_t)nN * 64 * 4);
    const size_t tier3End = off;
    const size_t aggBytes = (size_t)nN * 64 * 4;

    if (ws_size >= tier2End) {
        // ---- fast path: CSR + nodePart + small-LDS segmented edge kernel ----
        float* gsum = (ws_size >= tier3End) ? gsumw : out;  // aliasing out is safe (block-local RAW)
        const int nb = (nN + 2047) / 2048;
        hipMemsetAsync(counts, 0, (size_t)nN * 4, stream);
        hipMemsetAsync(gsum, 0, aggBytes, stream);
        hipLaunchKernelGGL(hist_kernel, dim3(2048), dim3(256), 0, stream, dstArr, counts, nE);
        hipLaunchKernelGGL(scan_local_kernel, dim3(nb), dim3(256), 0, stream, counts, offs, bsum, nN);
        hipLaunchKernelGGL(scan_bsums_kernel, dim3(1), dim3(64), 0, stream, bsum, nb);
        hipLaunchKernelGGL(scan_add_kernel, dim3(nb), dim3(256), 0, stream, offs, bsum, cursor, nN);
        hipLaunchKernelGGL(scatter_kernel, dim3(2048), dim3(256), 0, stream, ei, cursor, esd, nE);
        hipLaunchKernelGGL(prep_w23_kernel, dim3(1), dim3(256), 0, stream, W2, W3, b2, W23, b2w);
        hipLaunchKernelGGL(node_part_kernel, dim3(gridB), dim3(256), 0, stream, nf, W1, npart, nN);

        const int gridE = nTiles < 1536 ? nTiles : 1536;   // 6 blocks/CU resident
        hipLaunchKernelGGL(edge_np_kernel, dim3(gridE), dim3(256), 0, stream,
                           ef, esd, npart, W1, b1, gsum, nE, nTiles);

        hipLaunchKernelGGL(node_update_kernel, dim3(gridB), dim3(256), 0, stream,
                           nf, gsum, W3, W23, b3, b2w, counts, lns, lnb, out, nN);
    } else {
        // ---- fallback: block-tile edge kernel with per-edge atomics ----
        const int gridA = nTiles < 1024 ? nTiles : 1024;
        float* agg = (ws_size >= aggBytes) ? (float*)d_ws : out;
        hipMemsetAsync(agg, 0, aggBytes, stream);
        hipLaunchKernelGGL(edge_mlp_kernel, dim3(gridA), dim3(256), 0, stream,
                           nf, ef, ei, W1, b1, W2, b2, agg, nE, nTiles);
        hipLaunchKernelGGL(node_update_kernel, dim3(gridB), dim3(256), 0, stream,
                           nf, agg, W3, W3 + 64 * 64, b3, (const float*)nullptr, (const int*)nullptr,
                           lns, lnb, out, nN);
    }
}